// Round 1
// baseline (365.629 us; speedup 1.0000x reference)
//
#include <hip/hip_runtime.h>
#include <math.h>

// GNNAttention collapsed form:
//   out[b,n]  = dot_l(x[b,l,n], fc1_w[l]) + fc1_b
//   g[b,n]    = lin_b + rB + out[b,n]*rw48 + x_dist[n]*rw49
//               + (cnt>0 ? (1/cnt) * sum_{edges i: dst=n}(lB + out[b,src]*lw48 + x_dist[src]*lw49) : 0)
//   y[b,n]    = mask ? -1e8 : log_softmax_n(g[b,:])
// where rB/lB are per-b dots of [week_emb(34)|x_features(2)|x_embed(12)] with lin_{r,l}_w[0:48].

namespace {
constexpr int NNODE = 1000;
constexpr int LSTOP = 20;
constexpr int LBV   = 30;
constexpr int ESV   = 34;
constexpr int SESV  = 12;
constexpr int NFV   = 2;
}

__global__ __launch_bounds__(256) void gnn_fwd_kernel(
    const int*   __restrict__ stops,      // B x 20
    const float* __restrict__ x,          // B x 30 x 1000
    const float* __restrict__ x_dist,     // 1000
    const float* __restrict__ x_features, // B x 2
    const int*   __restrict__ x_week,     // B
    const int*   __restrict__ x_mask,     // B x 1000 (bool as int32)
    const float* __restrict__ stop_emb,   // 1000 x 12
    const float* __restrict__ week_emb,   // 7 x 34
    const float* __restrict__ fc1_w,      // 30
    const float* __restrict__ fc1_b,      // 1
    const float* __restrict__ lin_l_w,    // 50
    const float* __restrict__ lin_r_w,    // 50
    const float* __restrict__ lin_b,      // 1
    float*       __restrict__ out)        // B x 1000
{
  const int b = blockIdx.x;
  const int t = threadIdx.x;

  __shared__ float outs[NNODE];
  __shared__ float sacc[NNODE];
  __shared__ float cnts[NNODE];
  __shared__ float fc1w_s[LBV];
  __shared__ int   stops_s[LSTOP];
  __shared__ float xemb_s[SESV];
  __shared__ float pl_s[48];
  __shared__ float pr_s[48];
  __shared__ float red_s[8];
  __shared__ float scal_s[4];   // 0: lB, 1: rB, 2: row max, 3: row sumexp

  // ---- zero edge accumulators; stage tiny inputs ----
  for (int i = t; i < NNODE; i += 256) { sacc[i] = 0.f; cnts[i] = 0.f; }
  if (t < LSTOP) stops_s[t] = stops[b * LSTOP + t];
  if (t < LBV)   fc1w_s[t]  = fc1_w[t];
  __syncthreads();

  // ---- x_embed[b] = sum_l stop_emb[stops[b,l]] (12 components) ----
  if (t < SESV) {
    float e = 0.f;
    #pragma unroll
    for (int l = 0; l < LSTOP; ++l) e += stop_emb[stops_s[l] * SESV + t];
    xemb_s[t] = e;
  }
  __syncthreads();

  // ---- per-b 48-vector products with lin weights ----
  if (t < 48) {
    float v;
    if (t < ESV)            v = week_emb[x_week[b] * ESV + t];
    else if (t < ESV + NFV) v = x_features[b * NFV + (t - ESV)];
    else                    v = xemb_s[t - ESV - NFV];
    pl_s[t] = v * lin_l_w[t];
    pr_s[t] = v * lin_r_w[t];
  }
  __syncthreads();

  if (t == 0) {
    float sl = 0.f, sr = 0.f;
    #pragma unroll
    for (int k = 0; k < 48; ++k) { sl += pl_s[k]; sr += pr_s[k]; }
    scal_s[0] = sl; scal_s[1] = sr;
  }

  // ---- out[b,n]: the dominant 120 KB/row stream over x ----
  if (t < NNODE / 4) {
    const float fb = fc1_b[0];
    const float* xb = x + (size_t)b * LBV * NNODE + 4 * t;
    float4 acc = make_float4(fb, fb, fb, fb);
    #pragma unroll
    for (int l = 0; l < LBV; ++l) {
      const float4 v = *reinterpret_cast<const float4*>(xb + (size_t)l * NNODE);
      const float w = fc1w_s[l];
      acc.x = fmaf(v.x, w, acc.x);
      acc.y = fmaf(v.y, w, acc.y);
      acc.z = fmaf(v.z, w, acc.z);
      acc.w = fmaf(v.w, w, acc.w);
    }
    *reinterpret_cast<float4*>(&outs[4 * t]) = acc;
  }
  __syncthreads();

  // ---- 19-edge segment mean accumulation (LDS atomics) ----
  if (t < LSTOP - 1) {
    const int src = stops_s[t];
    const int dst = stops_s[t + 1];
    const float m = scal_s[0] + outs[src] * lin_l_w[48] + x_dist[src] * lin_l_w[49];
    atomicAdd(&sacc[dst], m);
    atomicAdd(&cnts[dst], 1.f);
  }
  __syncthreads();

  // ---- g[b,n] + local max ----
  const float rw48 = lin_r_w[48];
  const float rw49 = lin_r_w[49];
  const float base = lin_b[0] + scal_s[1];

  float g[4] = {0.f, 0.f, 0.f, 0.f};
  float lmax = -INFINITY;
  if (t < NNODE / 4) {
    #pragma unroll
    for (int j = 0; j < 4; ++j) {
      const int n = 4 * t + j;
      const float c = cnts[n];
      const float mean = (c > 0.f) ? (sacc[n] / c) : 0.f;
      g[j] = base + outs[n] * rw48 + x_dist[n] * rw49 + mean;
      lmax = fmaxf(lmax, g[j]);
    }
  }

  // ---- block max reduce (4 waves of 64) ----
  #pragma unroll
  for (int o = 32; o > 0; o >>= 1) lmax = fmaxf(lmax, __shfl_down(lmax, o));
  if ((t & 63) == 0) red_s[t >> 6] = lmax;
  __syncthreads();
  if (t == 0) scal_s[2] = fmaxf(fmaxf(red_s[0], red_s[1]), fmaxf(red_s[2], red_s[3]));
  __syncthreads();
  const float gmax = scal_s[2];

  // ---- block sum-exp reduce ----
  float lsum = 0.f;
  if (t < NNODE / 4) {
    #pragma unroll
    for (int j = 0; j < 4; ++j) lsum += expf(g[j] - gmax);
  }
  #pragma unroll
  for (int o = 32; o > 0; o >>= 1) lsum += __shfl_down(lsum, o);
  if ((t & 63) == 0) red_s[4 + (t >> 6)] = lsum;
  __syncthreads();
  if (t == 0) scal_s[3] = red_s[4] + red_s[5] + red_s[6] + red_s[7];
  __syncthreads();

  // ---- masked log-softmax write ----
  if (t < NNODE / 4) {
    const float lse = gmax + logf(scal_s[3]);
    const int4 mk = *reinterpret_cast<const int4*>(x_mask + (size_t)b * NNODE + 4 * t);
    float4 o;
    o.x = mk.x ? -100000000.0f : (g[0] - lse);
    o.y = mk.y ? -100000000.0f : (g[1] - lse);
    o.z = mk.z ? -100000000.0f : (g[2] - lse);
    o.w = mk.w ? -100000000.0f : (g[3] - lse);
    *reinterpret_cast<float4*>(out + (size_t)b * NNODE + 4 * t) = o;
  }
}

extern "C" void kernel_launch(void* const* d_in, const int* in_sizes, int n_in,
                              void* d_out, int out_size, void* d_ws, size_t ws_size,
                              hipStream_t stream) {
  const int*   stops      = (const int*)  d_in[0];
  const float* x          = (const float*)d_in[1];
  const float* x_dist     = (const float*)d_in[2];
  const float* x_features = (const float*)d_in[3];
  const int*   x_week     = (const int*)  d_in[4];
  const int*   x_mask     = (const int*)  d_in[5];
  const float* stop_emb   = (const float*)d_in[6];
  const float* week_emb   = (const float*)d_in[7];
  const float* fc1_w      = (const float*)d_in[8];
  const float* fc1_b      = (const float*)d_in[9];
  const float* lin_l_w    = (const float*)d_in[10];
  const float* lin_r_w    = (const float*)d_in[11];
  const float* lin_b      = (const float*)d_in[12];
  float* out = (float*)d_out;

  const int batch = in_sizes[4];  // x_week has B elements

  gnn_fwd_kernel<<<batch, 256, 0, stream>>>(
      stops, x, x_dist, x_features, x_week, x_mask,
      stop_emb, week_emb, fc1_w, fc1_b, lin_l_w, lin_r_w, lin_b, out);
}